// Round 4
// baseline (2045.326 us; speedup 1.0000x reference)
//
#include <hip/hip_runtime.h>
#include <hip/hip_bf16.h>

#define TT 200
#define NBATCH 256
#define HID 128
#define G4 512
#define VOC 50000

// waves_per_eu(2,2): pin allocator to exactly 2 waves/SIMD => 256-VGPR budget.
// R2 lesson: launch_bounds(512,1) let the allocator target 4 waves/EU => 128 VGPRs
// => ~100 regs/thread spilled => k2 spent its life reloading scratch (VALUBusy 12.5%).

// ---------------- Kernel 1: x_gates = gather(ET, seq) @ W + b (fp32!) ----------------
// bf16 x_gates empirically fatal (R0: absmax 0.656) — recurrence amplifies noise.
// grid 1600, block 512; 32 rows per block. wcol[128] perpetual => needs ~145 VGPRs.
__global__ __launch_bounds__(512)
__attribute__((amdgpu_waves_per_eu(2, 2)))
void k1_xgates(
    const int* __restrict__ seq,        // (T*N)
    const float* __restrict__ ET,       // (V, H)
    const float* __restrict__ W,        // (H, 4H)
    const float* __restrict__ b,        // (4H)
    float* __restrict__ xg)             // (T*N, 4H)
{
    const int tid = threadIdx.x;
    const int row0 = blockIdx.x * 32;
    __shared__ int idx[32];
    __shared__ __align__(16) float emb[32][HID];
    if (tid < 32) idx[tid] = seq[row0 + tid];
    __syncthreads();
    {
        const int r = tid >> 4;        // 0..31
        const int c = tid & 15;        // 16 chunks of 8 floats
        const float* src = ET + (size_t)idx[r] * HID + c * 8;
        float4 v0 = ((const float4*)src)[0];
        float4 v1 = ((const float4*)src)[1];
        ((float4*)&emb[r][c * 8])[0] = v0;
        ((float4*)&emb[r][c * 8])[1] = v1;
    }
    float wcol[HID];
    #pragma unroll
    for (int h = 0; h < HID; ++h) wcol[h] = W[(size_t)h * G4 + tid];
    const float bj = b[tid];
    __syncthreads();

    for (int r = 0; r < 32; ++r) {
        float a0 = bj, a1 = 0.f, a2 = 0.f, a3 = 0.f;
        const float4* e4 = (const float4*)&emb[r][0];
        #pragma unroll
        for (int q = 0; q < 32; ++q) {
            float4 e = e4[q];
            a0 = fmaf(e.x, wcol[4*q+0], a0);
            a1 = fmaf(e.y, wcol[4*q+1], a1);
            a2 = fmaf(e.z, wcol[4*q+2], a2);
            a3 = fmaf(e.w, wcol[4*q+3], a3);
        }
        xg[(size_t)(row0 + r) * G4 + tid] = (a0 + a1) + (a2 + a3);
    }
}

// ---------------- Kernel 2: sequential recurrence, one block of 512 per n ----------------
// Perpetual regs: ucol[128] + hreg[50] + creg[50] = 228 (+~20 temps) — fits the
// 256-VGPR budget pinned by waves_per_eu(2,2). 4 barriers/step.
__global__ __launch_bounds__(512)
__attribute__((amdgpu_waves_per_eu(2, 2)))
void k2_recur(
    const float* __restrict__ topo,     // (T, N, T)
    const float* __restrict__ mask,     // (T, N)
    const float* __restrict__ U,        // (H, 4H)
    const float* __restrict__ xg,       // (T*N, 4H) fp32
    float* __restrict__ hmean)          // (N, H)
{
    const int n   = blockIdx.x;
    const int tid = threadIdx.x;
    const int g   = tid >> 7;           // 0..3 (wave-uniform)
    const int h   = tid & 127;

    __shared__ __align__(16) float topoT[4][52]; // topoT[g][k] = topo[t][n][4k+g]
    __shared__ float part_h[4][HID];
    __shared__ float part_c[4][HID];
    __shared__ __align__(16) float hsum[HID];
    __shared__ float csum[HID];
    __shared__ float gates[G4];

    // each thread: full K=128 U column for gate column j=tid
    float ucol[128];
    #pragma unroll
    for (int k = 0; k < 128; ++k) ucol[k] = U[(size_t)k * G4 + tid];

    float hreg[50], creg[50];
    #pragma unroll
    for (int k = 0; k < 50; ++k) { hreg[k] = 0.f; creg[k] = 0.f; }

    float hmacc = 0.f;
    float len = 0.f;

    for (int t = 0; t < TT; ++t) {
        const size_t rowbase = (size_t)t * NBATCH + n;
        if (tid < TT) topoT[tid & 3][tid >> 2] = topo[rowbase * TT + tid];
        const float m = mask[(size_t)t * NBATCH + n];
        const float xgv = xg[rowbase * G4 + tid];
        __syncthreads();                                   // (1)

        // phase A: weighted history partials; rows >= t hold zeros (guards are perf-only)
        float ah0 = 0.f, ah1 = 0.f, ac0 = 0.f, ac1 = 0.f;
        const float4* tp4 = (const float4*)&topoT[g][0];   // wave-uniform broadcast reads
        #pragma unroll
        for (int kk = 0; kk < 12; ++kk) {
            if (16 * kk < t) {      // chunk rows start at 16*kk+g
                float4 tp = tp4[kk];
                ah0 = fmaf(tp.x, hreg[4*kk+0], ah0);
                ac0 = fmaf(tp.x, creg[4*kk+0], ac0);
                ah1 = fmaf(tp.y, hreg[4*kk+1], ah1);
                ac1 = fmaf(tp.y, creg[4*kk+1], ac1);
                ah0 = fmaf(tp.z, hreg[4*kk+2], ah0);
                ac0 = fmaf(tp.z, creg[4*kk+2], ac0);
                ah1 = fmaf(tp.w, hreg[4*kk+3], ah1);
                ac1 = fmaf(tp.w, creg[4*kk+3], ac1);
            }
        }
        if (192 < t) {  // tail k=48,49 (rows 192..199)
            const float tpx = topoT[g][48];
            const float tpy = topoT[g][49];
            ah0 = fmaf(tpx, hreg[48], ah0);
            ac0 = fmaf(tpx, creg[48], ac0);
            ah1 = fmaf(tpy, hreg[49], ah1);
            ac1 = fmaf(tpy, creg[49], ac1);
        }
        part_h[g][h] = ah0 + ah1;
        part_c[g][h] = ac0 + ac1;
        __syncthreads();                                   // (2)

        if (tid < HID) {
            hsum[tid] = ((part_h[0][tid] + part_h[1][tid]) +
                         (part_h[2][tid] + part_h[3][tid]));
        } else if (tid < 2 * HID) {
            const int hh = tid - HID;
            csum[hh] = ((part_c[0][hh] + part_c[1][hh]) +
                        (part_c[2][hh] + part_c[3][hh]));
        }
        __syncthreads();                                   // (3)

        // phase B: gates[j] = hsum . U[:,j] + x_gates[j]
        {
            float a0 = 0.f, a1 = 0.f, a2 = 0.f, a3 = 0.f;
            const float4* hs4 = (const float4*)hsum;       // broadcast b128 reads
            #pragma unroll
            for (int q = 0; q < 32; ++q) {
                float4 x = hs4[q];
                a0 = fmaf(x.x, ucol[4*q+0], a0);
                a1 = fmaf(x.y, ucol[4*q+1], a1);
                a2 = fmaf(x.z, ucol[4*q+2], a2);
                a3 = fmaf(x.w, ucol[4*q+3], a3);
            }
            gates[tid] = (a0 + a1) + (a2 + a3) + xgv;
        }
        __syncthreads();                                   // (4)

        // pointwise cell on owning group (wave-uniform branch); precise transcendentals
        if (g == (t & 3)) {
            const float iv = gates[h];
            const float fv = gates[HID + h];
            const float ov = gates[2 * HID + h];
            const float gv = gates[3 * HID + h];
            const float si = 1.f / (1.f + expf(-iv));
            const float sf = 1.f / (1.f + expf(-fv));
            const float so = 1.f / (1.f + expf(-ov));
            const float tg = tanhf(gv);
            const float cn = m * (sf * csum[h] + si * tg);
            const float hn = m * (so * tanhf(cn));
            const int kt = t >> 2;
            #pragma unroll
            for (int k = 0; k < 50; ++k) if (k == kt) { hreg[k] = hn; creg[k] = cn; }
            hmacc = fmaf(m, hn, hmacc);
        }
        len += m;
        // safe: every later write to {topoT,part,hsum,csum,gates} is separated from
        // this iteration's reads by at least one intervening barrier
    }

    part_h[g][h] = hmacc;
    __syncthreads();
    if (tid < HID) {
        const float s = ((part_h[0][tid] + part_h[1][tid]) +
                         (part_h[2][tid] + part_h[3][tid]));
        hmean[(size_t)n * HID + tid] = s / len;
    }
}

// ---------------- Kernel 3: out = h_mean @ W_out + b_out ----------------
// grid (98, 4), block 512; 512 cols x 64 rows per block. wcol[128] => ~145 VGPRs.
__global__ __launch_bounds__(512)
__attribute__((amdgpu_waves_per_eu(2, 2)))
void k3_out(
    const float* __restrict__ hm,      // (N, H)
    const float* __restrict__ Wout,    // (H, V)
    const float* __restrict__ bout,    // (V)
    float* __restrict__ out)           // (N, V)
{
    const int tid = threadIdx.x;
    const int v = blockIdx.x * 512 + tid;
    const int r0 = blockIdx.y * 64;
    __shared__ __align__(16) float hml[64][HID];
    {
        const int r = tid >> 3;        // 0..63
        const int c = tid & 7;         // 8 chunks of 16 floats
        const float4* src = (const float4*)(hm + (size_t)(r0 + r) * HID + c * 16);
        float4 a0 = src[0], a1 = src[1], a2 = src[2], a3 = src[3];
        float4* dst = (float4*)&hml[r][c * 16];
        dst[0] = a0; dst[1] = a1; dst[2] = a2; dst[3] = a3;
    }
    const int vc = v < VOC ? v : VOC - 1;
    float wcol[HID];
    #pragma unroll
    for (int h = 0; h < HID; ++h) wcol[h] = Wout[(size_t)h * VOC + vc];
    const float bj = bout[vc];
    __syncthreads();

    for (int r = 0; r < 64; ++r) {
        float a0 = bj, a1 = 0.f, a2 = 0.f, a3 = 0.f;
        const float4* hs4 = (const float4*)&hml[r][0];
        #pragma unroll
        for (int q = 0; q < 32; ++q) {
            float4 x = hs4[q];
            a0 = fmaf(x.x, wcol[4*q+0], a0);
            a1 = fmaf(x.y, wcol[4*q+1], a1);
            a2 = fmaf(x.z, wcol[4*q+2], a2);
            a3 = fmaf(x.w, wcol[4*q+3], a3);
        }
        if (v < VOC) out[(size_t)(r0 + r) * VOC + v] = (a0 + a1) + (a2 + a3);
    }
}

extern "C" void kernel_launch(void* const* d_in, const int* in_sizes, int n_in,
                              void* d_out, int out_size, void* d_ws, size_t ws_size,
                              hipStream_t stream) {
    const int*   seq  = (const int*)d_in[0];     // (T,N) int32
    const float* msk  = (const float*)d_in[1];   // (T,N)
    const float* topo = (const float*)d_in[2];   // (T,N,T)
    const float* W    = (const float*)d_in[3];   // (H,4H)
    const float* U    = (const float*)d_in[4];   // (H,4H)
    const float* b    = (const float*)d_in[5];   // (4H)
    const float* ET   = (const float*)d_in[6];   // (V,H)
    const float* Wout = (const float*)d_in[7];   // (H,V)
    const float* bout = (const float*)d_in[8];   // (V)
    float* out = (float*)d_out;

    const size_t xg_elems = (size_t)TT * NBATCH * G4;
    float* xg = (float*)d_ws;                                  // 104.9 MB fp32
    float* hmean = (float*)((char*)d_ws + xg_elems * sizeof(float));

    k1_xgates<<<1600, 512, 0, stream>>>(seq, ET, W, b, xg);
    k2_recur<<<NBATCH, 512, 0, stream>>>(topo, msk, U, xg, hmean);
    k3_out<<<dim3(98, 4), 512, 0, stream>>>(hmean, Wout, bout, out);
}

// Round 5
// 1022.653 us; speedup vs baseline: 2.0000x; 2.0000x over previous
//
#include <hip/hip_runtime.h>
#include <hip/hip_bf16.h>

#define TT 200
#define NBATCH 256
#define HID 128
#define G4 512
#define VOC 50000

// Design rule learned R1-R3: the backend pins 1024-thr blocks to <=128 VGPRs and
// 512-thr blocks to 128 unless it feels like more. So every kernel below is
// designed to need <= ~110 VGPRs. Block-uniform data goes through SGPRs
// (readfirstlane-forced uniformity -> s_load), bulk reuse goes to LDS.

// ---------------- Kernel XW: XW = ET @ W + b  (50000 x 512) ----------------
// 1024 thr: kh=tid>>9 (K half, wave-uniform), j=tid&511. wcol[64] in VGPRs,
// ET row values via scalar loads (uniform). Halves combined through LDS.
__global__ __launch_bounds__(1024) void kxw(
    const float* __restrict__ ET,       // (V, H)
    const float* __restrict__ W,        // (H, 4H)
    const float* __restrict__ b,        // (4H)
    float* __restrict__ XW)             // (V, 4H)
{
    const int tid = threadIdx.x;
    const int kh = __builtin_amdgcn_readfirstlane(tid >> 9);  // 0/1, wave-uniform
    const int j = tid & 511;
    const int rbase0 = blockIdx.x * 128;

    __shared__ __align__(16) float pA[16][2][G4];   // 64 KB

    float wcol[64];
    #pragma unroll
    for (int kk = 0; kk < 64; ++kk) wcol[kk] = W[(size_t)(kh * 64 + kk) * G4 + j];
    const float bj = b[j];

    for (int batch = 0; batch < 8; ++batch) {
        const int rb = rbase0 + batch * 16;
        float acc[16];
        #pragma unroll
        for (int r = 0; r < 16; ++r) {
            int row = rb + r; row = row < VOC ? row : VOC - 1;   // uniform
            const float* e = ET + (size_t)row * HID + kh * 64;   // uniform -> s_load
            float a0 = 0.f, a1 = 0.f, a2 = 0.f, a3 = 0.f;
            #pragma unroll
            for (int q = 0; q < 16; ++q) {
                a0 = fmaf(e[4*q+0], wcol[4*q+0], a0);
                a1 = fmaf(e[4*q+1], wcol[4*q+1], a1);
                a2 = fmaf(e[4*q+2], wcol[4*q+2], a2);
                a3 = fmaf(e[4*q+3], wcol[4*q+3], a3);
            }
            acc[r] = (a0 + a1) + (a2 + a3);
        }
        #pragma unroll
        for (int r = 0; r < 16; ++r) pA[r][kh][j] = acc[r];
        __syncthreads();
        if (tid < G4) {
            for (int r = 0; r < 16; ++r) {
                const int row = rb + r;
                if (row < VOC)
                    XW[(size_t)row * G4 + tid] = pA[r][0][tid] + pA[r][1][tid] + bj;
            }
        }
        __syncthreads();
    }
}

// ---------------- Kernel 2: recurrence, one 1024-thr block per n ----------------
// h history in regs (hreg[25], group g=tid>>7 owns rows [25g,25g+25)),
// c history in LDS (c_lds[h][209], pad 209 -> conflict-free),
// U in regs (ucol[64], K-half kh=tid>>9). Perpetual ~91 regs. 4 barriers/step.
__global__ __launch_bounds__(1024) void k2_recur(
    const float* __restrict__ topo,     // (T, N, T)
    const float* __restrict__ mask,     // (T, N)
    const float* __restrict__ U,        // (H, 4H)
    const int*   __restrict__ seq,      // (T, N)
    const float* __restrict__ XW,       // (V, 4H)
    float* __restrict__ hmT)            // (H, N) transposed h_mean
{
    const int n   = blockIdx.x;
    const int tid = threadIdx.x;
    const int g   = __builtin_amdgcn_readfirstlane(tid >> 7);   // 0..7
    const int h   = tid & 127;
    const int kh  = __builtin_amdgcn_readfirstlane(tid >> 9);   // 0..1
    const int j   = tid & 511;

    __shared__ float c_lds[HID][209];                 // 104.5 KB, c_lds[h][t']
    __shared__ __align__(16) float topoS[8][32];      // topoS[g][i] = topo row at 25g+i
    __shared__ float part_h[8][HID];
    __shared__ float part_c[8][HID];
    __shared__ __align__(16) float hsum[HID];
    __shared__ float csum[HID];
    __shared__ float pB[2][G4];
    __shared__ float xgl[2][G4];

    float ucol[64];
    #pragma unroll
    for (int kk = 0; kk < 64; ++kk) ucol[kk] = U[(size_t)(kh * 64 + kk) * G4 + j];

    float hreg[25];
    #pragma unroll
    for (int k = 0; k < 25; ++k) hreg[k] = 0.f;
    for (int i = tid; i < HID * 209; i += 1024) (&c_lds[0][0])[i] = 0.f;

    float hmacc = 0.f, len = 0.f;
    __syncthreads();

    for (int t = 0; t < TT; ++t) {
        // ---- stage: seq row of XW (coalesced 2KB), topo row (transposed-grouped) ----
        const int row = seq[t * NBATCH + n];                    // uniform s_load
        const float m = mask[t * NBATCH + n];                   // uniform
        if (tid < G4) xgl[t & 1][tid] = XW[(size_t)row * G4 + tid];
        if (tid < 256) {
            const int gg = tid >> 5, ii = tid & 31;
            topoS[gg][ii] = (ii < 25)
                ? topo[((size_t)t * NBATCH + n) * TT + 25 * gg + ii] : 0.f;
        }
        __syncthreads();                                        // (1)

        // ---- phase A: h partial from regs, c partial from LDS; rows >= t are zero ----
        float ah0 = 0.f, ah1 = 0.f, ac0 = 0.f, ac1 = 0.f;
        const int base = 25 * g;
        const float4* tp4 = (const float4*)&topoS[g][0];
        const float* crow = &c_lds[h][0];
        #pragma unroll
        for (int kk = 0; kk < 6; ++kk) {
            if (base + 4 * kk < t) {        // perf guard only; data is 0 beyond t
                float4 tp = tp4[kk];
                ah0 = fmaf(tp.x, hreg[4*kk+0], ah0);
                ac0 = fmaf(tp.x, crow[base+4*kk+0], ac0);
                ah1 = fmaf(tp.y, hreg[4*kk+1], ah1);
                ac1 = fmaf(tp.y, crow[base+4*kk+1], ac1);
                ah0 = fmaf(tp.z, hreg[4*kk+2], ah0);
                ac0 = fmaf(tp.z, crow[base+4*kk+2], ac0);
                ah1 = fmaf(tp.w, hreg[4*kk+3], ah1);
                ac1 = fmaf(tp.w, crow[base+4*kk+3], ac1);
            }
        }
        if (base + 24 < t) {
            const float tpl = topoS[g][24];
            ah0 = fmaf(tpl, hreg[24], ah0);
            ac0 = fmaf(tpl, crow[base+24], ac0);
        }
        part_h[g][h] = ah0 + ah1;
        part_c[g][h] = ac0 + ac1;
        __syncthreads();                                        // (2)

        if (tid < HID) {
            float s = 0.f;
            #pragma unroll
            for (int gg = 0; gg < 8; ++gg) s += part_h[gg][tid];
            hsum[tid] = s;
        } else if (tid < 2 * HID) {
            const int hh = tid - HID;
            float s = 0.f;
            #pragma unroll
            for (int gg = 0; gg < 8; ++gg) s += part_c[gg][hh];
            csum[hh] = s;
        }
        __syncthreads();                                        // (3)

        // ---- phase B: pB[kh][j] = hsum[kh-half] . U-half column ----
        {
            float a0 = 0.f, a1 = 0.f, a2 = 0.f, a3 = 0.f;
            const float4* hs4 = (const float4*)&hsum[kh * 64];
            #pragma unroll
            for (int q = 0; q < 16; ++q) {
                float4 x = hs4[q];
                a0 = fmaf(x.x, ucol[4*q+0], a0);
                a1 = fmaf(x.y, ucol[4*q+1], a1);
                a2 = fmaf(x.z, ucol[4*q+2], a2);
                a3 = fmaf(x.w, ucol[4*q+3], a3);
            }
            pB[kh][j] = (a0 + a1) + (a2 + a3);
        }
        __syncthreads();                                        // (4)

        // ---- cell: owning group g* = t/25 (wave-uniform branch) ----
        const int gstar = t / 25;
        if (g == gstar) {
            const int p = t & 1;
            const float iv = pB[0][h]       + pB[1][h]       + xgl[p][h];
            const float fv = pB[0][128+h]   + pB[1][128+h]   + xgl[p][128+h];
            const float ov = pB[0][256+h]   + pB[1][256+h]   + xgl[p][256+h];
            const float gv = pB[0][384+h]   + pB[1][384+h]   + xgl[p][384+h];
            const float si = 1.f / (1.f + expf(-iv));
            const float sf = 1.f / (1.f + expf(-fv));
            const float so = 1.f / (1.f + expf(-ov));
            const float tg = tanhf(gv);
            const float cn = m * (sf * csum[h] + si * tg);
            const float hn = m * (so * tanhf(cn));
            const int kt = t - 25 * gstar;
            #pragma unroll
            for (int k = 0; k < 25; ++k) if (k == kt) hreg[k] = hn;
            c_lds[h][t] = cn;
            hmacc = fmaf(m, hn, hmacc);
        }
        len += m;
        // next iter's writes are all behind barrier (1); xgl/pB double-buffered
        // or barrier-separated from this iter's cell reads.
    }

    part_h[g][h] = hmacc;     // unique slot per thread
    __syncthreads();
    if (tid < HID) {
        float s = 0.f;
        #pragma unroll
        for (int gg = 0; gg < 8; ++gg) s += part_h[gg][tid];
        hmT[(size_t)tid * NBATCH + n] = s / len;   // transposed for k3
    }
}

// ---------------- Kernel 3: out = h_mean @ W_out + b_out  (k-outer matvec) ----------------
// 512 thr: v = column; acc[32] rows; Wout coalesced, hmT row-slice via s_load.
__global__ __launch_bounds__(512) void k3_out(
    const float* __restrict__ hmT,     // (H, N)
    const float* __restrict__ Wout,    // (H, V)
    const float* __restrict__ bout,    // (V)
    float* __restrict__ out)           // (N, V)
{
    const int tid = threadIdx.x;
    const int v = blockIdx.x * 512 + tid;
    const int r0 = blockIdx.y * 32;
    const int vc = v < VOC ? v : VOC - 1;

    float acc[32];
    #pragma unroll
    for (int r = 0; r < 32; ++r) acc[r] = 0.f;

    #pragma unroll 2
    for (int k = 0; k < HID; ++k) {
        const float wv = Wout[(size_t)k * VOC + vc];   // coalesced vector load
        const float* hr = hmT + k * NBATCH + r0;       // uniform -> s_load
        #pragma unroll
        for (int r = 0; r < 32; ++r) acc[r] = fmaf(hr[r], wv, acc[r]);
    }
    const float bv = bout[vc];
    if (v < VOC) {
        for (int r = 0; r < 32; ++r)
            out[(size_t)(r0 + r) * VOC + v] = acc[r] + bv;
    }
}

extern "C" void kernel_launch(void* const* d_in, const int* in_sizes, int n_in,
                              void* d_out, int out_size, void* d_ws, size_t ws_size,
                              hipStream_t stream) {
    const int*   seq  = (const int*)d_in[0];     // (T,N) int32
    const float* msk  = (const float*)d_in[1];   // (T,N)
    const float* topo = (const float*)d_in[2];   // (T,N,T)
    const float* W    = (const float*)d_in[3];   // (H,4H)
    const float* U    = (const float*)d_in[4];   // (H,4H)
    const float* b    = (const float*)d_in[5];   // (4H)
    const float* ET   = (const float*)d_in[6];   // (V,H)
    const float* Wout = (const float*)d_in[7];   // (H,V)
    const float* bout = (const float*)d_in[8];   // (V)
    float* out = (float*)d_out;

    float* XW  = (float*)d_ws;                                   // 102.4 MB
    float* hmT = (float*)((char*)d_ws + (size_t)VOC * G4 * sizeof(float)); // +128 KB

    kxw<<<(VOC + 127) / 128, 1024, 0, stream>>>(ET, W, b, XW);
    k2_recur<<<NBATCH, 1024, 0, stream>>>(topo, msk, U, seq, XW, hmT);
    k3_out<<<dim3(98, 8), 512, 0, stream>>>(hmT, Wout, bout, out);
}